// Round 6
// baseline (1300.386 us; speedup 1.0000x reference)
//
#include <hip/hip_runtime.h>
#include <hip/hip_bf16.h>

#define NN 131072
#define EE 2097152
#define NBK 512
#define EPSS 1e-5f

typedef float f32x4 __attribute__((ext_vector_type(4)));
typedef short s16x8 __attribute__((ext_vector_type(8)));

static __device__ __forceinline__ ushort f2bf(float f) {
    uint u = __float_as_uint(f);
    u += 0x7fffu + ((u >> 16) & 1u);
    return (ushort)(u >> 16);
}
static __device__ __forceinline__ float bf2f(ushort h) {
    return __uint_as_float(((uint)h) << 16);
}

// ---------------- debug: leak ws_size through d_out if workspace too small ----------------

__global__ void dbg_kernel(float* __restrict__ out, float a, float b) {
    int i = threadIdx.x;
    if (i < 80) out[i] = (i == 0) ? a : ((i == 1) ? b : 0.f);
}

// ---------------- CSR build ----------------

__global__ void hist_kernel(const int* __restrict__ dst, int* __restrict__ deg) {
    int e = blockIdx.x * 256 + threadIdx.x;
    if (e < EE) atomicAdd(&deg[dst[e]], 1);
}

__global__ __launch_bounds__(1024) void scanA_kernel(const int* __restrict__ deg,
                                                     int* __restrict__ rp,
                                                     int* __restrict__ bsum) {
    __shared__ int sh[1024];
    int t = threadIdx.x;
    int base = blockIdx.x * 1024;
    int v = deg[base + t];
    sh[t] = v;
    __syncthreads();
    for (int off = 1; off < 1024; off <<= 1) {
        int x = (t >= off) ? sh[t - off] : 0;
        __syncthreads();
        sh[t] += x;
        __syncthreads();
    }
    rp[base + t + 1] = sh[t];
    if (t == 1023) bsum[blockIdx.x] = sh[t];
}

__global__ __launch_bounds__(128) void scanB_kernel(int* __restrict__ bsum, int* __restrict__ boff) {
    __shared__ int sh[128];
    int t = threadIdx.x;
    int v = bsum[t];
    sh[t] = v;
    __syncthreads();
    for (int off = 1; off < 128; off <<= 1) {
        int x = (t >= off) ? sh[t - off] : 0;
        __syncthreads();
        sh[t] += x;
        __syncthreads();
    }
    boff[t] = sh[t] - v;  // exclusive
}

__global__ __launch_bounds__(1024) void scanC_kernel(int* __restrict__ rp, const int* __restrict__ boff) {
    int t = threadIdx.x;
    int b = blockIdx.x;
    rp[b * 1024 + t + 1] += boff[b];
    if (b == 0 && t == 0) rp[0] = 0;
}

__global__ void initgb_kernel(const int* __restrict__ rp, int* __restrict__ gbkt) {
    int t = blockIdx.x * 256 + threadIdx.x;
    if (t < NBK) gbkt[t] = rp[t << 8];
}

// pass A: chunked binning into 512 coarse buckets (dst>>8); per-block LDS ticketing
__global__ __launch_bounds__(1024) void binA_kernel(const int* __restrict__ src,
                                                    const int* __restrict__ dst,
                                                    const float* __restrict__ ew,
                                                    int* __restrict__ gbkt,
                                                    int2* __restrict__ tmp) {
    __shared__ int hist[NBK];
    __shared__ int curs[NBK];
    int t = threadIdx.x;
    int e0 = blockIdx.x * 16384;
    if (t < NBK) hist[t] = 0;
    __syncthreads();
#pragma unroll
    for (int i = 0; i < 16; i++) {
        int e = e0 + i * 1024 + t;
        atomicAdd(&hist[dst[e] >> 8], 1);
    }
    __syncthreads();
    if (t < NBK) curs[t] = atomicAdd(&gbkt[t], hist[t]);
    __syncthreads();
#pragma unroll
    for (int i = 0; i < 16; i++) {
        int e = e0 + i * 1024 + t;
        int d = dst[e];
        int p = atomicAdd(&curs[d >> 8], 1);
        tmp[p] = make_int2(src[e] | ((d & 255) << 17), __float_as_int(ew[e]));
    }
}

// pass B: per-bucket node-level LDS ticketing; writes land in one ~32KB CSR window
__global__ __launch_bounds__(256) void binB_kernel(const int* __restrict__ rp,
                                                   const int2* __restrict__ tmp,
                                                   int2* __restrict__ ecw) {
    __shared__ int curs[256];
    int t = threadIdx.x;
    int nbase = blockIdx.x << 8;
    curs[t] = rp[nbase + t];
    __syncthreads();
    int beg = rp[nbase], end = rp[nbase + 256];
    for (int e = beg + t; e < end; e += 256) {
        int2 v = tmp[e];
        int dlow = (v.x >> 17) & 255;
        int p = atomicAdd(&curs[dlow], 1);
        ecw[p] = make_int2(v.x & 0x1FFFF, v.y);
    }
}

// ---------------- weight prep: bf16 MFMA B-fragment layouts ----------------
// layout: [ck][kc(4)][ot(8)][lane(64)][j(8)], elem = W[i= kc*32+(lane>>4)*8+j][o= ot*16+(lane&15)]

__global__ void prepw_conv(const float* __restrict__ w1, const float* __restrict__ w2,
                           const float* __restrict__ w3, ushort* __restrict__ wTb) {
    int idx = blockIdx.x * 256 + threadIdx.x;
    if (idx >= 9 * 16384) return;
    int j = idx & 7;
    int lane = (idx >> 3) & 63;
    int ot = (idx >> 9) & 7;
    int kc = (idx >> 12) & 3;
    int ck = idx >> 14;            // c*3+k
    int k = ck % 3, c = ck / 3;
    int i = kc * 32 + (lane >> 4) * 8 + j;
    int o = ot * 16 + (lane & 15);
    const float* w = (c == 0) ? w1 : ((c == 1) ? w2 : w3);
    wTb[idx] = f2bf(w[o * 384 + i * 3 + k]);
}

__global__ void prepw_g(const float* __restrict__ w0, const float* __restrict__ w1,
                        const float* __restrict__ w2, const float* __restrict__ w3,
                        const float* __restrict__ w4, const float* __restrict__ w5,
                        ushort* __restrict__ wGb) {
    int idx = blockIdx.x * 256 + threadIdx.x;
    if (idx >= 6 * 16384) return;
    int j = idx & 7;
    int lane = (idx >> 3) & 63;
    int ot = (idx >> 9) & 7;
    int kc = (idx >> 12) & 3;
    int m = idx >> 14;
    int i = kc * 32 + (lane >> 4) * 8 + j;
    int o = ot * 16 + (lane & 15);
    const float* w = (m == 0) ? w0 : ((m == 1) ? w1 : ((m == 2) ? w2 :
                     ((m == 3) ? w3 : ((m == 4) ? w4 : w5))));
    wGb[idx] = f2bf(w[i * 128 + o]);
}

// ---------------- fused dilated convs via MFMA + combine + BN stats ----------------

__global__ __launch_bounds__(256) void conv_kernel(const float* __restrict__ h,
        const ushort* __restrict__ wTb,
        const float* __restrict__ b1, const float* __restrict__ b2, const float* __restrict__ b3,
        ushort* __restrict__ o1, ushort* __restrict__ o2, ushort* __restrict__ o3,
        float* __restrict__ stats) {
    __shared__ char smem[17920];
    __shared__ float red[768];
    int t = threadIdx.x;
    int n0 = blockIdx.x * 64;

    for (int idx = t; idx < 768; idx += 256) red[idx] = 0.f;

    for (int idx = t; idx < 70 * 32; idx += 256) {
        int row = idx >> 5, c4 = idx & 31;
        int gn = n0 - 3 + row;
        float4 v = make_float4(0.f, 0.f, 0.f, 0.f);
        if (gn >= 0 && gn < NN) v = *(const float4*)&h[(size_t)gn * 128 + c4 * 4];
        ushort4 pk;
        pk.x = f2bf(v.x); pk.y = f2bf(v.y); pk.z = f2bf(v.z); pk.w = f2bf(v.w);
        *(ushort4*)(smem + ((row * 256 + c4 * 8) ^ ((row & 7) << 4))) = pk;
    }
    __syncthreads();

    int wv = t >> 6, lane = t & 63;
    int fbase = lane & 15, grp = lane >> 4;
    int cbb = grp << 4;

    f32x4 acc[3][2][4];
#pragma unroll
    for (int c = 0; c < 3; c++)
#pragma unroll
        for (int o2 = 0; o2 < 2; o2++)
#pragma unroll
            for (int rg = 0; rg < 4; rg++) acc[c][o2][rg] = (f32x4){0.f, 0.f, 0.f, 0.f};

#pragma unroll
    for (int ck = 0; ck < 9; ck++) {
        const int c = ck / 3, k = ck % 3;
        const int shift = (c + 1) * (k - 1);
#pragma unroll
        for (int kc = 0; kc < 4; kc++) {
            s16x8 bA = *(const s16x8*)(wTb + (size_t)(((ck * 4 + kc) * 8 + wv * 2) * 512 + lane * 8));
            s16x8 bB = *(const s16x8*)(wTb + (size_t)(((ck * 4 + kc) * 8 + wv * 2 + 1) * 512 + lane * 8));
#pragma unroll
            for (int rg = 0; rg < 4; rg++) {
                int rr = rg * 16 + fbase + 3 + shift;
                s16x8 a = *(const s16x8*)(smem + ((rr * 256 + kc * 64 + cbb) ^ ((rr & 7) << 4)));
                acc[c][0][rg] = __builtin_amdgcn_mfma_f32_16x16x32_bf16(a, bA, acc[c][0][rg], 0, 0, 0);
                acc[c][1][rg] = __builtin_amdgcn_mfma_f32_16x16x32_bf16(a, bB, acc[c][1][rg], 0, 0, 0);
            }
        }
    }

    __syncthreads();   // done reading staged x; reuse smem for output transpose

#pragma unroll
    for (int p = 0; p < 3; p++) {
        const int pa = p, pbx = (p + 1) % 3;
        const float* Ba = (p == 0) ? b1 : ((p == 1) ? b2 : b3);
        const float* Bb = (p == 0) ? b2 : ((p == 1) ? b3 : b1);
        ushort* Op = (p == 0) ? o1 : ((p == 1) ? o2 : o3);
#pragma unroll
        for (int o2 = 0; o2 < 2; o2++) {
            int f = (wv * 2 + o2) * 16 + fbase;
            float bba = Ba[f], bbb = Bb[f];
            float s = 0.f, ss = 0.f;
#pragma unroll
            for (int rg = 0; rg < 4; rg++) {
#pragma unroll
                for (int q = 0; q < 4; q++) {
                    float ca = acc[pa][o2][rg][q] + bba;
                    float cb = acc[pbx][o2][rg][q] + bbb;
                    float tv = fmaxf(ca, 0.f) + cb;
                    int nl = rg * 16 + grp * 4 + q;
                    *(ushort*)(smem + ((nl * 256 + f * 2) ^ ((nl & 7) << 4))) = f2bf(tv);
                    s += tv; ss += tv * tv;
                }
            }
            s  += __shfl_xor(s, 16);  s  += __shfl_xor(s, 32);
            ss += __shfl_xor(ss, 16); ss += __shfl_xor(ss, 32);
            if (lane < 16) {
                atomicAdd(&red[(2 * p) * 128 + f], s);
                atomicAdd(&red[(2 * p + 1) * 128 + f], ss);
            }
        }
        __syncthreads();
        for (int idx = t; idx < 1024; idx += 256) {
            int row = idx >> 4, c16 = idx & 15;
            uint4 v = *(const uint4*)(smem + ((row * 256 + c16 * 16) ^ ((row & 7) << 4)));
            *(uint4*)&Op[(size_t)(n0 + row) * 128 + c16 * 8] = v;
        }
        __syncthreads();
    }

    if (t < 128) {
#pragma unroll
        for (int p6 = 0; p6 < 6; p6++)
            atomicAdd(&stats[p6 * 128 + t], red[p6 * 128 + t]);
    }
}

// ---------------- BN finalize ----------------

__global__ __launch_bounds__(128) void bnfin_kernel(const float* __restrict__ stats,
                                                    const float* __restrict__ g,
                                                    const float* __restrict__ b,
                                                    float* __restrict__ scsh, int q0, int nq) {
    int d = threadIdx.x;
    for (int q = q0; q < q0 + nq; ++q) {
        float s  = stats[(2 * q) * 128 + d];
        float ss = stats[(2 * q + 1) * 128 + d];
        float mu  = s * (1.f / NN);
        float var = ss * (1.f / NN) - mu * mu;
        float sc = g[d] / sqrtf(var + EPSS);
        float sh = b[d] - mu * sc;
        scsh[q * 256 + d] = sc;
        scsh[q * 256 + 128 + d] = sh;
    }
}

// ---------------- fused triple gather (t1,t2,t3 share the edge stream) ----------------

__global__ __launch_bounds__(256) void gather3_kernel(const ushort* __restrict__ x1,
        const ushort* __restrict__ x2, const ushort* __restrict__ x3,
        const int* __restrict__ rp, const int2* __restrict__ ecw,
        const float* __restrict__ scsh,
        ushort* __restrict__ G1, ushort* __restrict__ G2, ushort* __restrict__ G3) {
    int t = threadIdx.x;
    int wid = blockIdx.x * 4 + (t >> 6);
    int lane = t & 63;
    uint lo = lane * 2;
    float2 sc1 = *(const float2*)&scsh[lo],       sh1 = *(const float2*)&scsh[128 + lo];
    float2 sc2 = *(const float2*)&scsh[256 + lo], sh2 = *(const float2*)&scsh[384 + lo];
    float2 sc3 = *(const float2*)&scsh[512 + lo], sh3 = *(const float2*)&scsh[640 + lo];
    int beg = rp[wid], end = rp[wid + 1];
    float a1x = 0.f, a1y = 0.f, a2x = 0.f, a2y = 0.f, a3x = 0.f, a3y = 0.f, sw = 0.f;

    for (int e0 = beg; e0 < end; e0 += 8) {
        int2 rec[8];
#pragma unroll
        for (int q = 0; q < 8; q++) {
            int i = e0 + q;
            int ic = (i < end) ? i : (end - 1);
            int2 v = ecw[ic];
            if (i >= end) v.y = 0;
            rec[q] = v;
        }
        uint u1[8], u2[8], u3[8];
#pragma unroll
        for (int q = 0; q < 8; q++) {
            uint off = ((uint)rec[q].x << 7) + lo;
            u1[q] = *(const uint*)&x1[off];
            u2[q] = *(const uint*)&x2[off];
            u3[q] = *(const uint*)&x3[off];
        }
#pragma unroll
        for (int q = 0; q < 8; q++) {
            float w = __int_as_float(rec[q].y);
            a1x = fmaf(w, __uint_as_float(u1[q] << 16), a1x);
            a1y = fmaf(w, __uint_as_float(u1[q] & 0xffff0000u), a1y);
            a2x = fmaf(w, __uint_as_float(u2[q] << 16), a2x);
            a2y = fmaf(w, __uint_as_float(u2[q] & 0xffff0000u), a2y);
            a3x = fmaf(w, __uint_as_float(u3[q] << 16), a3x);
            a3y = fmaf(w, __uint_as_float(u3[q] & 0xffff0000u), a3y);
            sw += w;
        }
    }

    a1x = fmaf(sw, sh1.x, a1x * sc1.x); a1y = fmaf(sw, sh1.y, a1y * sc1.y);
    a2x = fmaf(sw, sh2.x, a2x * sc2.x); a2y = fmaf(sw, sh2.y, a2y * sc2.y);
    a3x = fmaf(sw, sh3.x, a3x * sc3.x); a3y = fmaf(sw, sh3.y, a3y * sc3.y);
    size_t base = (size_t)wid * 128 + lo;
    *(uint*)&G1[base] = (uint)f2bf(a1x) | ((uint)f2bf(a1y) << 16);
    *(uint*)&G2[base] = (uint)f2bf(a2x) | ((uint)f2bf(a2y) << 16);
    *(uint*)&G3[base] = (uint)f2bf(a3x) | ((uint)f2bf(a3y) << 16);
}

// ---------------- single gather (+optional BN affine), batch 16 ----------------

__global__ __launch_bounds__(256) void gather_kernel(const ushort* __restrict__ xb,
        const int* __restrict__ rp, const int2* __restrict__ ecw,
        const float* __restrict__ scsh, ushort* __restrict__ G) {
    int t = threadIdx.x;
    int wid = blockIdx.x * 4 + (t >> 6);
    int lane = t & 63;
    uint lo = lane * 2;
    float scx = 1.f, scy = 1.f, shx = 0.f, shy = 0.f;
    if (scsh) {
        float2 sc = *(const float2*)&scsh[lo];
        float2 sh = *(const float2*)&scsh[128 + lo];
        scx = sc.x; scy = sc.y; shx = sh.x; shy = sh.y;
    }
    int beg = rp[wid], end = rp[wid + 1];
    float ax = 0.f, ay = 0.f, sw = 0.f;

    for (int e0 = beg; e0 < end; e0 += 16) {
        int2 rec[16];
#pragma unroll
        for (int q = 0; q < 16; q++) {
            int i = e0 + q;
            int ic = (i < end) ? i : (end - 1);
            int2 v = ecw[ic];
            if (i >= end) v.y = 0;
            rec[q] = v;
        }
        uint u[16];
#pragma unroll
        for (int q = 0; q < 16; q++)
            u[q] = *(const uint*)&xb[((uint)rec[q].x << 7) + lo];
#pragma unroll
        for (int q = 0; q < 16; q++) {
            float w = __int_as_float(rec[q].y);
            ax = fmaf(w, __uint_as_float(u[q] << 16), ax);
            ay = fmaf(w, __uint_as_float(u[q] & 0xffff0000u), ay);
            sw += w;
        }
    }

    if (scsh) {
        ax = fmaf(sw, shx, ax * scx);
        ay = fmaf(sw, shy, ay * scy);
    }
    *(uint*)&G[(size_t)wid * 128 + lo] = (uint)f2bf(ax) | ((uint)f2bf(ay) << 16);
}

// ---------------- MFMA GEMM: Y = relu(X @ W + b), bf16 in/out ----------------

__global__ __launch_bounds__(256) void gemm_kernel(const ushort* __restrict__ X,
        const ushort* __restrict__ wF, const float* __restrict__ bias,
        ushort* __restrict__ Y) {
    __shared__ char smem[16384];
    int t = threadIdx.x;
    int n0 = blockIdx.x * 64;
    int wv = t >> 6, lane = t & 63;

    s16x8 bfrag[4][2];
#pragma unroll
    for (int kc = 0; kc < 4; kc++)
#pragma unroll
        for (int o2 = 0; o2 < 2; o2++)
            bfrag[kc][o2] = *(const s16x8*)(wF + (size_t)((kc * 8 + wv * 2 + o2) * 512 + lane * 8));

    for (int idx = t; idx < 1024; idx += 256) {
        int row = idx >> 4, c16 = idx & 15;
        uint4 v = *(const uint4*)&X[(size_t)(n0 + row) * 128 + c16 * 8];
        *(uint4*)(smem + ((row * 256 + c16 * 16) ^ ((row & 7) << 4))) = v;
    }
    __syncthreads();

    int fbase = lane & 15, grp = lane >> 4, cbb = grp << 4;
    f32x4 acc[2][4];
#pragma unroll
    for (int o2 = 0; o2 < 2; o2++)
#pragma unroll
        for (int rg = 0; rg < 4; rg++) acc[o2][rg] = (f32x4){0.f, 0.f, 0.f, 0.f};

#pragma unroll
    for (int kc = 0; kc < 4; kc++) {
#pragma unroll
        for (int rg = 0; rg < 4; rg++) {
            int rr = rg * 16 + fbase;
            s16x8 a = *(const s16x8*)(smem + ((rr * 256 + kc * 64 + cbb) ^ ((rr & 7) << 4)));
            acc[0][rg] = __builtin_amdgcn_mfma_f32_16x16x32_bf16(a, bfrag[kc][0], acc[0][rg], 0, 0, 0);
            acc[1][rg] = __builtin_amdgcn_mfma_f32_16x16x32_bf16(a, bfrag[kc][1], acc[1][rg], 0, 0, 0);
        }
    }

    __syncthreads();
#pragma unroll
    for (int o2 = 0; o2 < 2; o2++) {
        int f = (wv * 2 + o2) * 16 + fbase;
        float bb = bias[f];
#pragma unroll
        for (int rg = 0; rg < 4; rg++)
#pragma unroll
            for (int q = 0; q < 4; q++) {
                float y = fmaxf(acc[o2][rg][q] + bb, 0.f);
                int nl = rg * 16 + grp * 4 + q;
                *(ushort*)(smem + ((nl * 256 + f * 2) ^ ((nl & 7) << 4))) = f2bf(y);
            }
    }
    __syncthreads();
    for (int idx = t; idx < 1024; idx += 256) {
        int row = idx >> 4, c16 = idx & 15;
        uint4 v = *(const uint4*)(smem + ((row * 256 + c16 * 16) ^ ((row & 7) << 4)));
        *(uint4*)&Y[(size_t)(n0 + row) * 128 + c16 * 8] = v;
    }
}

// ---------------- press (1x3x3 conv over [N,3,D]) + BN stats (bf16 I/O) ----------------

__global__ __launch_bounds__(256) void press_kernel(const ushort* __restrict__ a1,
                                                    const ushort* __restrict__ a2,
                                                    const ushort* __restrict__ a3,
                                                    const float* __restrict__ pw,
                                                    const float* __restrict__ pb_,
                                                    ushort* __restrict__ out,
                                                    float* __restrict__ stats) {
    __shared__ float rows[6 * 128];
    __shared__ float red[512];
    int t = threadIdx.x;
    int d = t & 127, r = t >> 7;
    int n0 = blockIdx.x * 64;
    float w[9];
#pragma unroll
    for (int q = 0; q < 9; q++) w[q] = pw[q];
    float pb = pb_[0];

    float s = 0.f, ss = 0.f;
    for (int it = 0; it < 32; ++it) {
        int npair = n0 + it * 2;
#pragma unroll
        for (int q = 0; q < 3; q++) {
            int idx = q * 256 + t;
            int row = idx >> 7, col = idx & 127;
            int c = row >> 1, rr = row & 1;
            size_t off = (size_t)(npair + rr) * 128 + col;
            ushort v = (c == 0) ? a1[off] : ((c == 1) ? a2[off] : a3[off]);
            rows[row * 128 + col] = bf2f(v);
        }
        __syncthreads();
        const float* R1 = &rows[(0 + r) * 128];
        const float* R2 = &rows[(2 + r) * 128];
        const float* R3 = &rows[(4 + r) * 128];
        float m1 = (d > 0) ? R1[d - 1] : 0.f;
        float m2 = (d > 0) ? R2[d - 1] : 0.f;
        float m3 = (d > 0) ? R3[d - 1] : 0.f;
        float p1 = (d < 127) ? R1[d + 1] : 0.f;
        float p2 = (d < 127) ? R2[d + 1] : 0.f;
        float p3 = (d < 127) ? R3[d + 1] : 0.f;
        float v = pb;
        v = fmaf(w[0], m1, v); v = fmaf(w[1], R1[d], v); v = fmaf(w[2], p1, v);
        v = fmaf(w[3], m2, v); v = fmaf(w[4], R2[d], v); v = fmaf(w[5], p2, v);
        v = fmaf(w[6], m3, v); v = fmaf(w[7], R3[d], v); v = fmaf(w[8], p3, v);
        out[(size_t)(npair + r) * 128 + d] = f2bf(v);
        s += v; ss += v * v;
        __syncthreads();
    }
    red[t] = s; red[256 + t] = ss;
    __syncthreads();
    if (t < 128) {
        atomicAdd(&stats[6 * 128 + t], red[t] + red[t + 128]);
        atomicAdd(&stats[7 * 128 + t], red[256 + t] + red[256 + t + 128]);
    }
}

// ---------------- graph pooling (gid sorted), bf16 inputs ----------------

__global__ __launch_bounds__(256) void pool_kernel(const ushort* __restrict__ x2,
                                                   const ushort* __restrict__ x3,
                                                   const ushort* __restrict__ x4,
                                                   const int* __restrict__ gid,
                                                   float* __restrict__ hg) {
    int t = threadIdx.x;
    int d = t & 127, r = t >> 7;
    int n0 = blockIdx.x * 64;
    float a2 = 0.f, a3 = 0.f, a4 = 0.f;
    int g = gid[n0 + r];
    for (int it = 0; it < 32; ++it) {
        int n = n0 + it * 2 + r;
        int gn = gid[n];
        if (gn != g) {
            atomicAdd(&hg[g * 384 + d], a2);
            atomicAdd(&hg[g * 384 + 128 + d], a3);
            atomicAdd(&hg[g * 384 + 256 + d], a4);
            a2 = a3 = a4 = 0.f;
            g = gn;
        }
        size_t base = (size_t)n * 128 + d;
        a2 += bf2f(x2[base]); a3 += bf2f(x3[base]); a4 += bf2f(x4[base]);
    }
    atomicAdd(&hg[g * 384 + d], a2);
    atomicAdd(&hg[g * 384 + 128 + d], a3);
    atomicAdd(&hg[g * 384 + 256 + d], a4);
}

// ---------------- final classifier ----------------

__global__ __launch_bounds__(128) void final_kernel(const float* __restrict__ hg,
                                                    const float* __restrict__ w1,
                                                    const float* __restrict__ b1,
                                                    const float* __restrict__ w2,
                                                    const float* __restrict__ b2,
                                                    float* __restrict__ out) {
    __shared__ float hgs[16 * 384];
    __shared__ float tmp[16 * 128];
    int t = threadIdx.x;
    for (int idx = t; idx < 16 * 384; idx += 128) hgs[idx] = hg[idx];
    __syncthreads();
    for (int g = 0; g < 16; ++g) {
        float acc = b1[t];
        for (int k = 0; k < 384; k++) acc = fmaf(hgs[g * 384 + k], w1[t * 384 + k], acc);
        tmp[g * 128 + t] = acc;
    }
    __syncthreads();
    if (t < 80) {
        int g = t / 5, c = t % 5;
        float acc = b2[c];
        for (int j = 0; j < 128; j++) acc = fmaf(tmp[g * 128 + j], w2[c * 128 + j], acc);
        out[g * 5 + c] = acc;
    }
}

// ---------------- launch ----------------

extern "C" void kernel_launch(void* const* d_in, const int* in_sizes, int n_in,
                              void* d_out, int out_size, void* d_ws, size_t ws_size,
                              hipStream_t stream) {
    (void)in_sizes; (void)n_in; (void)out_size;

    const float* h        = (const float*)d_in[0];
    const float* edge_w   = (const float*)d_in[1];
    const int*   src      = (const int*)d_in[2];
    const int*   dst      = (const int*)d_in[3];
    const int*   node_gid = (const int*)d_in[4];
    const float* c1w = (const float*)d_in[6];
    const float* c1b = (const float*)d_in[7];
    const float* c2w = (const float*)d_in[8];
    const float* c2b = (const float*)d_in[9];
    const float* c3w = (const float*)d_in[10];
    const float* c3b = (const float*)d_in[11];
    const float* pw  = (const float*)d_in[12];
    const float* pb  = (const float*)d_in[13];
    const float* g11w = (const float*)d_in[14];
    const float* g11b = (const float*)d_in[15];
    const float* g12w = (const float*)d_in[16];
    const float* g12b = (const float*)d_in[17];
    const float* g13w = (const float*)d_in[18];
    const float* g13b = (const float*)d_in[19];
    const float* g2w = (const float*)d_in[20];
    const float* g2b = (const float*)d_in[21];
    const float* g3w = (const float*)d_in[22];
    const float* g3b = (const float*)d_in[23];
    const float* g4w = (const float*)d_in[24];
    const float* g4b = (const float*)d_in[25];
    const float* bng = (const float*)d_in[26];
    const float* bnb = (const float*)d_in[27];
    const float* cls1w = (const float*)d_in[28];
    const float* cls1b = (const float*)d_in[29];
    const float* cls2w = (const float*)d_in[30];
    const float* cls2b = (const float*)d_in[31];

    const size_t NW = (size_t)NN * 128;
    ushort* U1 = (ushort*)d_ws;
    ushort* U2 = U1 + NW;
    ushort* U3 = U2 + NW;
    ushort* U4 = U3 + NW;
    ushort* G1 = U4 + NW;
    ushort* G2 = G1 + NW;
    ushort* G3 = G2 + NW;
    int2*   tmp = (int2*)G1;                  // overlay: used only before gathers
    int2*   ecw = (int2*)(G3 + NW);           // E * 8B
    float*  stats = (float*)(ecw + EE);       // 8*128
    float*  scsh  = stats + 1024;             // 4*256
    ushort* wTb   = (ushort*)(scsh + 1024);   // 9*16384 bf16 frags (conv)
    ushort* wGb   = wTb + 9 * 16384;          // 6*16384 bf16 frags (gconv)
    float*  hg    = (float*)(wGb + 6 * 16384); // 16*384
    int*    rp    = (int*)(hg + 16 * 384);    // N+1
    int*    deg   = rp + (NN + 1);            // N
    int*    bsum  = deg + NN;                 // 128
    int*    boff  = bsum + 128;               // 128
    int*    gbkt  = boff + 128;               // 512
    size_t required = (size_t)((char*)(gbkt + NBK) - (char*)d_ws);

    if (ws_size < required) {
        dbg_kernel<<<1, 128, 0, stream>>>((float*)d_out, (float)ws_size,
                                          (float)(ws_size >> 20));
        return;
    }

    hipMemsetAsync(deg, 0, (size_t)NN * 4, stream);
    hipMemsetAsync(stats, 0, 1024 * 4, stream);
    hipMemsetAsync(hg, 0, (size_t)16 * 384 * 4, stream);

    // CSR build (bucketed 2-pass scatter)
    hist_kernel<<<EE / 256, 256, 0, stream>>>(dst, deg);
    scanA_kernel<<<128, 1024, 0, stream>>>(deg, rp, bsum);
    scanB_kernel<<<1, 128, 0, stream>>>(bsum, boff);
    scanC_kernel<<<128, 1024, 0, stream>>>(rp, boff);
    initgb_kernel<<<2, 256, 0, stream>>>(rp, gbkt);
    binA_kernel<<<128, 1024, 0, stream>>>(src, dst, edge_w, gbkt, tmp);
    binB_kernel<<<NBK, 256, 0, stream>>>(rp, tmp, ecw);

    // weight prep (bf16 fragment layouts)
    prepw_conv<<<576, 256, 0, stream>>>(c1w, c2w, c3w, wTb);
    prepw_g<<<384, 256, 0, stream>>>(g11w, g12w, g13w, g2w, g3w, g4w, wGb);

    // conv path: U1=t1, U2=t2, U3=t3 (bf16) + BN stats
    conv_kernel<<<NN / 64, 256, 0, stream>>>(h, wTb, c1b, c2b, c3b, U1, U2, U3, stats);
    bnfin_kernel<<<1, 128, 0, stream>>>(stats, bng, bnb, scsh, 0, 3);

    // fused triple gather (BN affines fused) -> G1,G2,G3; then 3 MFMA GEMMs
    gather3_kernel<<<NN / 4, 256, 0, stream>>>(U1, U2, U3, rp, ecw, scsh, G1, G2, G3);
    gemm_kernel<<<NN / 64, 256, 0, stream>>>(G1, wGb + 0 * 16384, g11b, U4);  // a1
    gemm_kernel<<<NN / 64, 256, 0, stream>>>(G2, wGb + 1 * 16384, g12b, U1);  // a2
    gemm_kernel<<<NN / 64, 256, 0, stream>>>(G3, wGb + 2 * 16384, g13b, U2);  // a3

    // press(a1,a2,a3) -> U3 (= ac_h1 pre-BN) + stats
    press_kernel<<<NN / 64, 256, 0, stream>>>(U4, U1, U2, pw, pb, U3, stats);
    bnfin_kernel<<<1, 128, 0, stream>>>(stats, bng, bnb, scsh, 3, 1);

    // chained gconvs: ac_h2 -> U4, ac_h3 -> U1, ac_h4 -> U2
    gather_kernel<<<NN / 4, 256, 0, stream>>>(U3, rp, ecw, scsh + 3 * 256, G2);
    gemm_kernel<<<NN / 64, 256, 0, stream>>>(G2, wGb + 3 * 16384, g2b, U4);
    gather_kernel<<<NN / 4, 256, 0, stream>>>(U4, rp, ecw, nullptr, G2);
    gemm_kernel<<<NN / 64, 256, 0, stream>>>(G2, wGb + 4 * 16384, g3b, U1);
    gather_kernel<<<NN / 4, 256, 0, stream>>>(U1, rp, ecw, nullptr, G2);
    gemm_kernel<<<NN / 64, 256, 0, stream>>>(G2, wGb + 5 * 16384, g4b, U2);

    // pooling + classifier
    pool_kernel<<<NN / 64, 256, 0, stream>>>(U4, U1, U2, node_gid, hg);
    final_kernel<<<1, 128, 0, stream>>>(hg, cls1w, cls1b, cls2w, cls2b, (float*)d_out);
}

// Round 8
// 1249.889 us; speedup vs baseline: 1.0404x; 1.0404x over previous
//
#include <hip/hip_runtime.h>
#include <hip/hip_bf16.h>

#define NN 131072
#define EE 2097152
#define NBK 512
#define EPSS 1e-5f

typedef float f32x4 __attribute__((ext_vector_type(4)));
typedef short s16x8 __attribute__((ext_vector_type(8)));

static __device__ __forceinline__ ushort f2bf(float f) {
    uint u = __float_as_uint(f);
    u += 0x7fffu + ((u >> 16) & 1u);
    return (ushort)(u >> 16);
}
static __device__ __forceinline__ float bf2f(ushort h) {
    return __uint_as_float(((uint)h) << 16);
}

// ---------------- debug: leak ws_size through d_out if workspace too small ----------------

__global__ void dbg_kernel(float* __restrict__ out, float a, float b) {
    int i = threadIdx.x;
    if (i < 80) out[i] = (i == 0) ? a : ((i == 1) ? b : 0.f);
}

// ---------------- CSR build ----------------

__global__ void hist_kernel(const int* __restrict__ dst, int* __restrict__ deg) {
    int e = blockIdx.x * 256 + threadIdx.x;
    if (e < EE) atomicAdd(&deg[dst[e]], 1);
}

__global__ __launch_bounds__(1024) void scanA_kernel(const int* __restrict__ deg,
                                                     int* __restrict__ rp,
                                                     int* __restrict__ bsum) {
    __shared__ int sh[1024];
    int t = threadIdx.x;
    int base = blockIdx.x * 1024;
    int v = deg[base + t];
    sh[t] = v;
    __syncthreads();
    for (int off = 1; off < 1024; off <<= 1) {
        int x = (t >= off) ? sh[t - off] : 0;
        __syncthreads();
        sh[t] += x;
        __syncthreads();
    }
    rp[base + t + 1] = sh[t];
    if (t == 1023) bsum[blockIdx.x] = sh[t];
}

__global__ __launch_bounds__(128) void scanB_kernel(int* __restrict__ bsum, int* __restrict__ boff) {
    __shared__ int sh[128];
    int t = threadIdx.x;
    int v = bsum[t];
    sh[t] = v;
    __syncthreads();
    for (int off = 1; off < 128; off <<= 1) {
        int x = (t >= off) ? sh[t - off] : 0;
        __syncthreads();
        sh[t] += x;
        __syncthreads();
    }
    boff[t] = sh[t] - v;  // exclusive
}

__global__ __launch_bounds__(1024) void scanC_kernel(int* __restrict__ rp, const int* __restrict__ boff) {
    int t = threadIdx.x;
    int b = blockIdx.x;
    rp[b * 1024 + t + 1] += boff[b];
    if (b == 0 && t == 0) rp[0] = 0;
}

__global__ void initgb_kernel(const int* __restrict__ rp, int* __restrict__ gbkt) {
    int t = blockIdx.x * 256 + threadIdx.x;
    if (t < NBK) gbkt[t] = rp[t << 8];
}

// pass A: chunked binning into 512 coarse buckets (dst>>8); per-block LDS ticketing
__global__ __launch_bounds__(1024) void binA_kernel(const int* __restrict__ src,
                                                    const int* __restrict__ dst,
                                                    const float* __restrict__ ew,
                                                    int* __restrict__ gbkt,
                                                    int2* __restrict__ tmp) {
    __shared__ int hist[NBK];
    __shared__ int curs[NBK];
    int t = threadIdx.x;
    int e0 = blockIdx.x * 16384;
    if (t < NBK) hist[t] = 0;
    __syncthreads();
#pragma unroll
    for (int i = 0; i < 16; i++) {
        int e = e0 + i * 1024 + t;
        atomicAdd(&hist[dst[e] >> 8], 1);
    }
    __syncthreads();
    if (t < NBK) curs[t] = atomicAdd(&gbkt[t], hist[t]);
    __syncthreads();
#pragma unroll
    for (int i = 0; i < 16; i++) {
        int e = e0 + i * 1024 + t;
        int d = dst[e];
        int p = atomicAdd(&curs[d >> 8], 1);
        tmp[p] = make_int2(src[e] | ((d & 255) << 17), __float_as_int(ew[e]));
    }
}

// pass B: per-bucket node-level LDS ticketing; writes land in one ~32KB CSR window
__global__ __launch_bounds__(256) void binB_kernel(const int* __restrict__ rp,
                                                   const int2* __restrict__ tmp,
                                                   int2* __restrict__ ecw) {
    __shared__ int curs[256];
    int t = threadIdx.x;
    int nbase = blockIdx.x << 8;
    curs[t] = rp[nbase + t];
    __syncthreads();
    int beg = rp[nbase], end = rp[nbase + 256];
    for (int e = beg + t; e < end; e += 256) {
        int2 v = tmp[e];
        int dlow = (v.x >> 17) & 255;
        int p = atomicAdd(&curs[dlow], 1);
        ecw[p] = make_int2(v.x & 0x1FFFF, v.y);
    }
}

// ---------------- weight prep: bf16 MFMA B-fragment layouts ----------------
// layout: [ck][kc(4)][ot(8)][lane(64)][j(8)], elem = W[i= kc*32+(lane>>4)*8+j][o= ot*16+(lane&15)]

__global__ void prepw_conv(const float* __restrict__ w1, const float* __restrict__ w2,
                           const float* __restrict__ w3, ushort* __restrict__ wTb) {
    int idx = blockIdx.x * 256 + threadIdx.x;
    if (idx >= 9 * 16384) return;
    int j = idx & 7;
    int lane = (idx >> 3) & 63;
    int ot = (idx >> 9) & 7;
    int kc = (idx >> 12) & 3;
    int ck = idx >> 14;            // c*3+k
    int k = ck % 3, c = ck / 3;
    int i = kc * 32 + (lane >> 4) * 8 + j;
    int o = ot * 16 + (lane & 15);
    const float* w = (c == 0) ? w1 : ((c == 1) ? w2 : w3);
    wTb[idx] = f2bf(w[o * 384 + i * 3 + k]);
}

__global__ void prepw_g(const float* __restrict__ w0, const float* __restrict__ w1,
                        const float* __restrict__ w2, const float* __restrict__ w3,
                        const float* __restrict__ w4, const float* __restrict__ w5,
                        ushort* __restrict__ wGb) {
    int idx = blockIdx.x * 256 + threadIdx.x;
    if (idx >= 6 * 16384) return;
    int j = idx & 7;
    int lane = (idx >> 3) & 63;
    int ot = (idx >> 9) & 7;
    int kc = (idx >> 12) & 3;
    int m = idx >> 14;
    int i = kc * 32 + (lane >> 4) * 8 + j;
    int o = ot * 16 + (lane & 15);
    const float* w = (m == 0) ? w0 : ((m == 1) ? w1 : ((m == 2) ? w2 :
                     ((m == 3) ? w3 : ((m == 4) ? w4 : w5))));
    wGb[idx] = f2bf(w[i * 128 + o]);
}

// ---------------- fused dilated convs via MFMA + combine + BN stats ----------------

__global__ __launch_bounds__(256) void conv_kernel(const float* __restrict__ h,
        const ushort* __restrict__ wTb,
        const float* __restrict__ b1, const float* __restrict__ b2, const float* __restrict__ b3,
        ushort* __restrict__ o1, ushort* __restrict__ o2, ushort* __restrict__ o3,
        float* __restrict__ stats) {
    __shared__ char smem[17920];
    __shared__ float red[768];
    int t = threadIdx.x;
    int n0 = blockIdx.x * 64;

    for (int idx = t; idx < 768; idx += 256) red[idx] = 0.f;

    for (int idx = t; idx < 70 * 32; idx += 256) {
        int row = idx >> 5, c4 = idx & 31;
        int gn = n0 - 3 + row;
        float4 v = make_float4(0.f, 0.f, 0.f, 0.f);
        if (gn >= 0 && gn < NN) v = *(const float4*)&h[(size_t)gn * 128 + c4 * 4];
        ushort4 pk;
        pk.x = f2bf(v.x); pk.y = f2bf(v.y); pk.z = f2bf(v.z); pk.w = f2bf(v.w);
        *(ushort4*)(smem + ((row * 256 + c4 * 8) ^ ((row & 7) << 4))) = pk;
    }
    __syncthreads();

    int wv = t >> 6, lane = t & 63;
    int fbase = lane & 15, grp = lane >> 4;
    int cbb = grp << 4;

    f32x4 acc[3][2][4];
#pragma unroll
    for (int c = 0; c < 3; c++)
#pragma unroll
        for (int o2 = 0; o2 < 2; o2++)
#pragma unroll
            for (int rg = 0; rg < 4; rg++) acc[c][o2][rg] = (f32x4){0.f, 0.f, 0.f, 0.f};

#pragma unroll
    for (int ck = 0; ck < 9; ck++) {
        const int c = ck / 3, k = ck % 3;
        const int shift = (c + 1) * (k - 1);
#pragma unroll
        for (int kc = 0; kc < 4; kc++) {
            s16x8 bA = *(const s16x8*)(wTb + (size_t)(((ck * 4 + kc) * 8 + wv * 2) * 512 + lane * 8));
            s16x8 bB = *(const s16x8*)(wTb + (size_t)(((ck * 4 + kc) * 8 + wv * 2 + 1) * 512 + lane * 8));
#pragma unroll
            for (int rg = 0; rg < 4; rg++) {
                int rr = rg * 16 + fbase + 3 + shift;
                s16x8 a = *(const s16x8*)(smem + ((rr * 256 + kc * 64 + cbb) ^ ((rr & 7) << 4)));
                acc[c][0][rg] = __builtin_amdgcn_mfma_f32_16x16x32_bf16(a, bA, acc[c][0][rg], 0, 0, 0);
                acc[c][1][rg] = __builtin_amdgcn_mfma_f32_16x16x32_bf16(a, bB, acc[c][1][rg], 0, 0, 0);
            }
        }
    }

    __syncthreads();   // done reading staged x; reuse smem for output transpose

#pragma unroll
    for (int p = 0; p < 3; p++) {
        const int pa = p, pbx = (p + 1) % 3;
        const float* Ba = (p == 0) ? b1 : ((p == 1) ? b2 : b3);
        const float* Bb = (p == 0) ? b2 : ((p == 1) ? b3 : b1);
        ushort* Op = (p == 0) ? o1 : ((p == 1) ? o2 : o3);
#pragma unroll
        for (int o2 = 0; o2 < 2; o2++) {
            int f = (wv * 2 + o2) * 16 + fbase;
            float bba = Ba[f], bbb = Bb[f];
            float s = 0.f, ss = 0.f;
#pragma unroll
            for (int rg = 0; rg < 4; rg++) {
#pragma unroll
                for (int q = 0; q < 4; q++) {
                    float ca = acc[pa][o2][rg][q] + bba;
                    float cb = acc[pbx][o2][rg][q] + bbb;
                    float tv = fmaxf(ca, 0.f) + cb;
                    int nl = rg * 16 + grp * 4 + q;
                    *(ushort*)(smem + ((nl * 256 + f * 2) ^ ((nl & 7) << 4))) = f2bf(tv);
                    s += tv; ss += tv * tv;
                }
            }
            s  += __shfl_xor(s, 16);  s  += __shfl_xor(s, 32);
            ss += __shfl_xor(ss, 16); ss += __shfl_xor(ss, 32);
            if (lane < 16) {
                atomicAdd(&red[(2 * p) * 128 + f], s);
                atomicAdd(&red[(2 * p + 1) * 128 + f], ss);
            }
        }
        __syncthreads();
        for (int idx = t; idx < 1024; idx += 256) {
            int row = idx >> 4, c16 = idx & 15;
            uint4 v = *(const uint4*)(smem + ((row * 256 + c16 * 16) ^ ((row & 7) << 4)));
            *(uint4*)&Op[(size_t)(n0 + row) * 128 + c16 * 8] = v;
        }
        __syncthreads();
    }

    if (t < 128) {
#pragma unroll
        for (int p6 = 0; p6 < 6; p6++)
            atomicAdd(&stats[p6 * 128 + t], red[p6 * 128 + t]);
    }
}

// ---------------- BN finalize ----------------

__global__ __launch_bounds__(128) void bnfin_kernel(const float* __restrict__ stats,
                                                    const float* __restrict__ g,
                                                    const float* __restrict__ b,
                                                    float* __restrict__ scsh, int q0, int nq) {
    int d = threadIdx.x;
    for (int q = q0; q < q0 + nq; ++q) {
        float s  = stats[(2 * q) * 128 + d];
        float ss = stats[(2 * q + 1) * 128 + d];
        float mu  = s * (1.f / NN);
        float var = ss * (1.f / NN) - mu * mu;
        float sc = g[d] / sqrtf(var + EPSS);
        float sh = b[d] - mu * sc;
        scsh[q * 256 + d] = sc;
        scsh[q * 256 + 128 + d] = sh;
    }
}

// ---------------- gather helpers: statically-unrolled batch-8 primitives ----------------

static __device__ __forceinline__ void loadrec8(int2* r, const int2* __restrict__ ecw,
                                                int e0, int end) {
#pragma unroll
    for (int q = 0; q < 8; q++) {
        int i = e0 + q;
        int ic = (i < end) ? i : (end - 1);
        int2 v = ecw[ic];
        if (i >= end) v.y = 0;
        r[q] = v;
    }
}

static __device__ __forceinline__ void loadrow8(uint* u, const ushort* __restrict__ xb,
                                                const int2* r, uint lo) {
#pragma unroll
    for (int q = 0; q < 8; q++)
        u[q] = *(const uint*)&xb[((uint)r[q].x << 7) + lo];
}

static __device__ __forceinline__ void fma8(float& ax, float& ay, float& sw,
                                            const uint* u, const int2* r) {
#pragma unroll
    for (int q = 0; q < 8; q++) {
        float w = __int_as_float(r[q].y);
        ax = fmaf(w, __uint_as_float(u[q] << 16), ax);
        ay = fmaf(w, __uint_as_float(u[q] & 0xffff0000u), ay);
        sw += w;
    }
}

// ---------------- fused triple gather, 2-deep software pipeline ----------------
// recs loaded 2 batches ahead, rows 1 batch ahead, FMA on current batch.

__global__ __launch_bounds__(256) void gather3_kernel(const ushort* __restrict__ x1,
        const ushort* __restrict__ x2, const ushort* __restrict__ x3,
        const int* __restrict__ rp, const int2* __restrict__ ecw,
        const float* __restrict__ scsh,
        ushort* __restrict__ G1, ushort* __restrict__ G2, ushort* __restrict__ G3) {
    int t = threadIdx.x;
    int wid = blockIdx.x * 4 + (t >> 6);
    int lane = t & 63;
    uint lo = lane * 2;
    float2 sc1 = *(const float2*)&scsh[lo],       sh1 = *(const float2*)&scsh[128 + lo];
    float2 sc2 = *(const float2*)&scsh[256 + lo], sh2 = *(const float2*)&scsh[384 + lo];
    float2 sc3 = *(const float2*)&scsh[512 + lo], sh3 = *(const float2*)&scsh[640 + lo];
    int beg = rp[wid], end = rp[wid + 1];
    int nb = (end - beg + 7) >> 3;
    float a1x = 0.f, a1y = 0.f, a2x = 0.f, a2y = 0.f, a3x = 0.f, a3y = 0.f, sw = 0.f;

    if (nb > 0) {
        int2 rC[8], rN[8], rF[8];
        uint u1C[8], u2C[8], u3C[8], u1N[8], u2N[8], u3N[8];
        loadrec8(rC, ecw, beg, end);
        if (nb > 1) loadrec8(rN, ecw, beg + 8, end);
        loadrow8(u1C, x1, rC, lo);
        loadrow8(u2C, x2, rC, lo);
        loadrow8(u3C, x3, rC, lo);
        for (int b = 0; b < nb; b++) {
            if (b + 1 < nb) {
                loadrow8(u1N, x1, rN, lo);
                loadrow8(u2N, x2, rN, lo);
                loadrow8(u3N, x3, rN, lo);
            }
            if (b + 2 < nb) loadrec8(rF, ecw, beg + (b + 2) * 8, end);
            fma8(a1x, a1y, sw, u1C, rC);
            float dum = 0.f;
            fma8(a2x, a2y, dum, u2C, rC);
            fma8(a3x, a3y, dum, u3C, rC);
#pragma unroll
            for (int q = 0; q < 8; q++) {
                rC[q] = rN[q]; rN[q] = rF[q];
                u1C[q] = u1N[q]; u2C[q] = u2N[q]; u3C[q] = u3N[q];
            }
        }
    }

    a1x = fmaf(sw, sh1.x, a1x * sc1.x); a1y = fmaf(sw, sh1.y, a1y * sc1.y);
    a2x = fmaf(sw, sh2.x, a2x * sc2.x); a2y = fmaf(sw, sh2.y, a2y * sc2.y);
    a3x = fmaf(sw, sh3.x, a3x * sc3.x); a3y = fmaf(sw, sh3.y, a3y * sc3.y);
    size_t base = (size_t)wid * 128 + lo;
    *(uint*)&G1[base] = (uint)f2bf(a1x) | ((uint)f2bf(a1y) << 16);
    *(uint*)&G2[base] = (uint)f2bf(a2x) | ((uint)f2bf(a2y) << 16);
    *(uint*)&G3[base] = (uint)f2bf(a3x) | ((uint)f2bf(a3y) << 16);
}

// ---------------- single gather (+optional BN affine), 2-deep software pipeline ----------------

__global__ __launch_bounds__(256) void gather_kernel(const ushort* __restrict__ xb,
        const int* __restrict__ rp, const int2* __restrict__ ecw,
        const float* __restrict__ scsh, ushort* __restrict__ G) {
    int t = threadIdx.x;
    int wid = blockIdx.x * 4 + (t >> 6);
    int lane = t & 63;
    uint lo = lane * 2;
    float scx = 1.f, scy = 1.f, shx = 0.f, shy = 0.f;
    if (scsh) {
        float2 sc = *(const float2*)&scsh[lo];
        float2 sh = *(const float2*)&scsh[128 + lo];
        scx = sc.x; scy = sc.y; shx = sh.x; shy = sh.y;
    }
    int beg = rp[wid], end = rp[wid + 1];
    int nb = (end - beg + 7) >> 3;
    float ax = 0.f, ay = 0.f, sw = 0.f;

    if (nb > 0) {
        int2 rC[8], rN[8], rF[8];
        uint uC[8], uN[8];
        loadrec8(rC, ecw, beg, end);
        if (nb > 1) loadrec8(rN, ecw, beg + 8, end);
        loadrow8(uC, xb, rC, lo);
        for (int b = 0; b < nb; b++) {
            if (b + 1 < nb) loadrow8(uN, xb, rN, lo);
            if (b + 2 < nb) loadrec8(rF, ecw, beg + (b + 2) * 8, end);
            fma8(ax, ay, sw, uC, rC);
#pragma unroll
            for (int q = 0; q < 8; q++) {
                rC[q] = rN[q]; rN[q] = rF[q]; uC[q] = uN[q];
            }
        }
    }

    if (scsh) {
        ax = fmaf(sw, shx, ax * scx);
        ay = fmaf(sw, shy, ay * scy);
    }
    *(uint*)&G[(size_t)wid * 128 + lo] = (uint)f2bf(ax) | ((uint)f2bf(ay) << 16);
}

// ---------------- MFMA GEMM: Y = relu(X @ W + b), bf16 in/out ----------------

__global__ __launch_bounds__(256) void gemm_kernel(const ushort* __restrict__ X,
        const ushort* __restrict__ wF, const float* __restrict__ bias,
        ushort* __restrict__ Y) {
    __shared__ char smem[16384];
    int t = threadIdx.x;
    int n0 = blockIdx.x * 64;
    int wv = t >> 6, lane = t & 63;

    s16x8 bfrag[4][2];
#pragma unroll
    for (int kc = 0; kc < 4; kc++)
#pragma unroll
        for (int o2 = 0; o2 < 2; o2++)
            bfrag[kc][o2] = *(const s16x8*)(wF + (size_t)((kc * 8 + wv * 2 + o2) * 512 + lane * 8));

    for (int idx = t; idx < 1024; idx += 256) {
        int row = idx >> 4, c16 = idx & 15;
        uint4 v = *(const uint4*)&X[(size_t)(n0 + row) * 128 + c16 * 8];
        *(uint4*)(smem + ((row * 256 + c16 * 16) ^ ((row & 7) << 4))) = v;
    }
    __syncthreads();

    int fbase = lane & 15, grp = lane >> 4, cbb = grp << 4;
    f32x4 acc[2][4];
#pragma unroll
    for (int o2 = 0; o2 < 2; o2++)
#pragma unroll
        for (int rg = 0; rg < 4; rg++) acc[o2][rg] = (f32x4){0.f, 0.f, 0.f, 0.f};

#pragma unroll
    for (int kc = 0; kc < 4; kc++) {
#pragma unroll
        for (int rg = 0; rg < 4; rg++) {
            int rr = rg * 16 + fbase;
            s16x8 a = *(const s16x8*)(smem + ((rr * 256 + kc * 64 + cbb) ^ ((rr & 7) << 4)));
            acc[0][rg] = __builtin_amdgcn_mfma_f32_16x16x32_bf16(a, bfrag[kc][0], acc[0][rg], 0, 0, 0);
            acc[1][rg] = __builtin_amdgcn_mfma_f32_16x16x32_bf16(a, bfrag[kc][1], acc[1][rg], 0, 0, 0);
        }
    }

    __syncthreads();
#pragma unroll
    for (int o2 = 0; o2 < 2; o2++) {
        int f = (wv * 2 + o2) * 16 + fbase;
        float bb = bias[f];
#pragma unroll
        for (int rg = 0; rg < 4; rg++)
#pragma unroll
            for (int q = 0; q < 4; q++) {
                float y = fmaxf(acc[o2][rg][q] + bb, 0.f);
                int nl = rg * 16 + grp * 4 + q;
                *(ushort*)(smem + ((nl * 256 + f * 2) ^ ((nl & 7) << 4))) = f2bf(y);
            }
    }
    __syncthreads();
    for (int idx = t; idx < 1024; idx += 256) {
        int row = idx >> 4, c16 = idx & 15;
        uint4 v = *(const uint4*)(smem + ((row * 256 + c16 * 16) ^ ((row & 7) << 4)));
        *(uint4*)&Y[(size_t)(n0 + row) * 128 + c16 * 8] = v;
    }
}

// ---------------- press (1x3x3 conv over [N,3,D]) + BN stats (bf16 I/O) ----------------

__global__ __launch_bounds__(256) void press_kernel(const ushort* __restrict__ a1,
                                                    const ushort* __restrict__ a2,
                                                    const ushort* __restrict__ a3,
                                                    const float* __restrict__ pw,
                                                    const float* __restrict__ pb_,
                                                    ushort* __restrict__ out,
                                                    float* __restrict__ stats) {
    __shared__ float rows[6 * 128];
    __shared__ float red[512];
    int t = threadIdx.x;
    int d = t & 127, r = t >> 7;
    int n0 = blockIdx.x * 64;
    float w[9];
#pragma unroll
    for (int q = 0; q < 9; q++) w[q] = pw[q];
    float pb = pb_[0];

    float s = 0.f, ss = 0.f;
    for (int it = 0; it < 32; ++it) {
        int npair = n0 + it * 2;
#pragma unroll
        for (int q = 0; q < 3; q++) {
            int idx = q * 256 + t;
            int row = idx >> 7, col = idx & 127;
            int c = row >> 1, rr = row & 1;
            size_t off = (size_t)(npair + rr) * 128 + col;
            ushort v = (c == 0) ? a1[off] : ((c == 1) ? a2[off] : a3[off]);
            rows[row * 128 + col] = bf2f(v);
        }
        __syncthreads();
        const float* R1 = &rows[(0 + r) * 128];
        const float* R2 = &rows[(2 + r) * 128];
        const float* R3 = &rows[(4 + r) * 128];
        float m1 = (d > 0) ? R1[d - 1] : 0.f;
        float m2 = (d > 0) ? R2[d - 1] : 0.f;
        float m3 = (d > 0) ? R3[d - 1] : 0.f;
        float p1 = (d < 127) ? R1[d + 1] : 0.f;
        float p2 = (d < 127) ? R2[d + 1] : 0.f;
        float p3 = (d < 127) ? R3[d + 1] : 0.f;
        float v = pb;
        v = fmaf(w[0], m1, v); v = fmaf(w[1], R1[d], v); v = fmaf(w[2], p1, v);
        v = fmaf(w[3], m2, v); v = fmaf(w[4], R2[d], v); v = fmaf(w[5], p2, v);
        v = fmaf(w[6], m3, v); v = fmaf(w[7], R3[d], v); v = fmaf(w[8], p3, v);
        out[(size_t)(npair + r) * 128 + d] = f2bf(v);
        s += v; ss += v * v;
        __syncthreads();
    }
    red[t] = s; red[256 + t] = ss;
    __syncthreads();
    if (t < 128) {
        atomicAdd(&stats[6 * 128 + t], red[t] + red[t + 128]);
        atomicAdd(&stats[7 * 128 + t], red[256 + t] + red[256 + t + 128]);
    }
}

// ---------------- graph pooling (gid sorted), bf16 inputs ----------------

__global__ __launch_bounds__(256) void pool_kernel(const ushort* __restrict__ x2,
                                                   const ushort* __restrict__ x3,
                                                   const ushort* __restrict__ x4,
                                                   const int* __restrict__ gid,
                                                   float* __restrict__ hg) {
    int t = threadIdx.x;
    int d = t & 127, r = t >> 7;
    int n0 = blockIdx.x * 64;
    float a2 = 0.f, a3 = 0.f, a4 = 0.f;
    int g = gid[n0 + r];
    for (int it = 0; it < 32; ++it) {
        int n = n0 + it * 2 + r;
        int gn = gid[n];
        if (gn != g) {
            atomicAdd(&hg[g * 384 + d], a2);
            atomicAdd(&hg[g * 384 + 128 + d], a3);
            atomicAdd(&hg[g * 384 + 256 + d], a4);
            a2 = a3 = a4 = 0.f;
            g = gn;
        }
        size_t base = (size_t)n * 128 + d;
        a2 += bf2f(x2[base]); a3 += bf2f(x3[base]); a4 += bf2f(x4[base]);
    }
    atomicAdd(&hg[g * 384 + d], a2);
    atomicAdd(&hg[g * 384 + 128 + d], a3);
    atomicAdd(&hg[g * 384 + 256 + d], a4);
}

// ---------------- final classifier ----------------

__global__ __launch_bounds__(128) void final_kernel(const float* __restrict__ hg,
                                                    const float* __restrict__ w1,
                                                    const float* __restrict__ b1,
                                                    const float* __restrict__ w2,
                                                    const float* __restrict__ b2,
                                                    float* __restrict__ out) {
    __shared__ float hgs[16 * 384];
    __shared__ float tmp[16 * 128];
    int t = threadIdx.x;
    for (int idx = t; idx < 16 * 384; idx += 128) hgs[idx] = hg[idx];
    __syncthreads();
    for (int g = 0; g < 16; ++g) {
        float acc = b1[t];
        for (int k = 0; k < 384; k++) acc = fmaf(hgs[g * 384 + k], w1[t * 384 + k], acc);
        tmp[g * 128 + t] = acc;
    }
    __syncthreads();
    if (t < 80) {
        int g = t / 5, c = t % 5;
        float acc = b2[c];
        for (int j = 0; j < 128; j++) acc = fmaf(tmp[g * 128 + j], w2[c * 128 + j], acc);
        out[g * 5 + c] = acc;
    }
}

// ---------------- launch ----------------

extern "C" void kernel_launch(void* const* d_in, const int* in_sizes, int n_in,
                              void* d_out, int out_size, void* d_ws, size_t ws_size,
                              hipStream_t stream) {
    (void)in_sizes; (void)n_in; (void)out_size;

    const float* h        = (const float*)d_in[0];
    const float* edge_w   = (const float*)d_in[1];
    const int*   src      = (const int*)d_in[2];
    const int*   dst      = (const int*)d_in[3];
    const int*   node_gid = (const int*)d_in[4];
    const float* c1w = (const float*)d_in[6];
    const float* c1b = (const float*)d_in[7];
    const float* c2w = (const float*)d_in[8];
    const float* c2b = (const float*)d_in[9];
    const float* c3w = (const float*)d_in[10];
    const float* c3b = (const float*)d_in[11];
    const float* pw  = (const float*)d_in[12];
    const float* pb  = (const float*)d_in[13];
    const float* g11w = (const float*)d_in[14];
    const float* g11b = (const float*)d_in[15];
    const float* g12w = (const float*)d_in[16];
    const float* g12b = (const float*)d_in[17];
    const float* g13w = (const float*)d_in[18];
    const float* g13b = (const float*)d_in[19];
    const float* g2w = (const float*)d_in[20];
    const float* g2b = (const float*)d_in[21];
    const float* g3w = (const float*)d_in[22];
    const float* g3b = (const float*)d_in[23];
    const float* g4w = (const float*)d_in[24];
    const float* g4b = (const float*)d_in[25];
    const float* bng = (const float*)d_in[26];
    const float* bnb = (const float*)d_in[27];
    const float* cls1w = (const float*)d_in[28];
    const float* cls1b = (const float*)d_in[29];
    const float* cls2w = (const float*)d_in[30];
    const float* cls2b = (const float*)d_in[31];

    const size_t NW = (size_t)NN * 128;
    ushort* U1 = (ushort*)d_ws;
    ushort* U2 = U1 + NW;
    ushort* U3 = U2 + NW;
    ushort* U4 = U3 + NW;
    ushort* G1 = U4 + NW;
    ushort* G2 = G1 + NW;
    ushort* G3 = G2 + NW;
    int2*   tmp = (int2*)G1;                  // overlay: used only before gathers
    int2*   ecw = (int2*)(G3 + NW);           // E * 8B
    float*  stats = (float*)(ecw + EE);       // 8*128
    float*  scsh  = stats + 1024;             // 4*256
    ushort* wTb   = (ushort*)(scsh + 1024);   // 9*16384 bf16 frags (conv)
    ushort* wGb   = wTb + 9 * 16384;          // 6*16384 bf16 frags (gconv)
    float*  hg    = (float*)(wGb + 6 * 16384); // 16*384
    int*    rp    = (int*)(hg + 16 * 384);    // N+1
    int*    deg   = rp + (NN + 1);            // N
    int*    bsum  = deg + NN;                 // 128
    int*    boff  = bsum + 128;               // 128
    int*    gbkt  = boff + 128;               // 512
    size_t required = (size_t)((char*)(gbkt + NBK) - (char*)d_ws);

    if (ws_size < required) {
        dbg_kernel<<<1, 128, 0, stream>>>((float*)d_out, (float)ws_size,
                                          (float)(ws_size >> 20));
        return;
    }

    hipMemsetAsync(deg, 0, (size_t)NN * 4, stream);
    hipMemsetAsync(stats, 0, 1024 * 4, stream);
    hipMemsetAsync(hg, 0, (size_t)16 * 384 * 4, stream);

    // CSR build (bucketed 2-pass scatter)
    hist_kernel<<<EE / 256, 256, 0, stream>>>(dst, deg);
    scanA_kernel<<<128, 1024, 0, stream>>>(deg, rp, bsum);
    scanB_kernel<<<1, 128, 0, stream>>>(bsum, boff);
    scanC_kernel<<<128, 1024, 0, stream>>>(rp, boff);
    initgb_kernel<<<2, 256, 0, stream>>>(rp, gbkt);
    binA_kernel<<<128, 1024, 0, stream>>>(src, dst, edge_w, gbkt, tmp);
    binB_kernel<<<NBK, 256, 0, stream>>>(rp, tmp, ecw);

    // weight prep (bf16 fragment layouts)
    prepw_conv<<<576, 256, 0, stream>>>(c1w, c2w, c3w, wTb);
    prepw_g<<<384, 256, 0, stream>>>(g11w, g12w, g13w, g2w, g3w, g4w, wGb);

    // conv path: U1=t1, U2=t2, U3=t3 (bf16) + BN stats
    conv_kernel<<<NN / 64, 256, 0, stream>>>(h, wTb, c1b, c2b, c3b, U1, U2, U3, stats);
    bnfin_kernel<<<1, 128, 0, stream>>>(stats, bng, bnb, scsh, 0, 3);

    // fused triple gather (BN affines fused) -> G1,G2,G3; then 3 MFMA GEMMs
    gather3_kernel<<<NN / 4, 256, 0, stream>>>(U1, U2, U3, rp, ecw, scsh, G1, G2, G3);
    gemm_kernel<<<NN / 64, 256, 0, stream>>>(G1, wGb + 0 * 16384, g11b, U4);  // a1
    gemm_kernel<<<NN / 64, 256, 0, stream>>>(G2, wGb + 1 * 16384, g12b, U1);  // a2
    gemm_kernel<<<NN / 64, 256, 0, stream>>>(G3, wGb + 2 * 16384, g13b, U2);  // a3

    // press(a1,a2,a3) -> U3 (= ac_h1 pre-BN) + stats
    press_kernel<<<NN / 64, 256, 0, stream>>>(U4, U1, U2, pw, pb, U3, stats);
    bnfin_kernel<<<1, 128, 0, stream>>>(stats, bng, bnb, scsh, 3, 1);

    // chained gconvs: ac_h2 -> U4, ac_h3 -> U1, ac_h4 -> U2
    gather_kernel<<<NN / 4, 256, 0, stream>>>(U3, rp, ecw, scsh + 3 * 256, G2);
    gemm_kernel<<<NN / 64, 256, 0, stream>>>(G2, wGb + 3 * 16384, g2b, U4);
    gather_kernel<<<NN / 4, 256, 0, stream>>>(U4, rp, ecw, nullptr, G2);
    gemm_kernel<<<NN / 64, 256, 0, stream>>>(G2, wGb + 4 * 16384, g3b, U1);
    gather_kernel<<<NN / 4, 256, 0, stream>>>(U1, rp, ecw, nullptr, G2);
    gemm_kernel<<<NN / 64, 256, 0, stream>>>(G2, wGb + 5 * 16384, g4b, U2);

    // pooling + classifier
    pool_kernel<<<NN / 64, 256, 0, stream>>>(U4, U1, U2, node_gid, hg);
    final_kernel<<<1, 128, 0, stream>>>(hg, cls1w, cls1b, cls2w, cls2b, (float*)d_out);
}